// Round 1
// baseline (413.873 us; speedup 1.0000x reference)
//
#include <hip/hip_runtime.h>
#include <math.h>

#define RESERVE 16384
#define IMG_CPLX 65536            // 256*256 complex per image
#define IMG_BYTES (IMG_CPLX * 8)  // float2

__device__ __forceinline__ float2 cadd(float2 a, float2 b){ return make_float2(a.x+b.x, a.y+b.y); }
__device__ __forceinline__ float2 csub(float2 a, float2 b){ return make_float2(a.x-b.x, a.y-b.y); }
__device__ __forceinline__ float2 cmul(float2 a, float2 b){ return make_float2(a.x*b.x - a.y*b.y, a.x*b.y + a.y*b.x); }

// 256-point Stockham radix-4 FFT, 64 lanes (one wave) per FFT.
// A: data in/out (256 float2, contiguous). S: scratch (256 float2).
// DIR=-1 forward (exp(-2pi i)), DIR=+1 inverse (unnormalized).
// All exchange is intra-wave via LDS; per-wave LDS ops complete in order,
// so no barriers are needed inside.
template<int DIR>
__device__ __forceinline__ void fft256(float2* A, float2* S, int lane) {
  float2* src = A;
  float2* dst = S;
  int m = 1;
  #pragma unroll
  for (int s = 0; s < 4; ++s) {
    int j  = lane / m;       // m is 1,4,16,64 (compile-time after unroll)
    int k  = lane - j * m;
    int jm = j * m;
    float2 c0 = src[lane];
    float2 c1 = src[lane + 64];
    float2 c2 = src[lane + 128];
    float2 c3 = src[lane + 192];
    float2 t0 = cadd(c0, c2);
    float2 t1 = csub(c0, c2);
    float2 t2 = cadd(c1, c3);
    float2 d  = csub(c1, c3);
    float2 t3 = (DIR < 0) ? make_float2(d.y, -d.x) : make_float2(-d.y, d.x);
    // w1 = exp(DIR * 2*pi*i * jm / 256) ; angle in units of pi: DIR*jm/128
    float a = (float)DIR * (float)jm * (1.0f / 128.0f);
    float sw, cw;
    sincospif(a, &sw, &cw);
    float2 w1 = make_float2(cw, sw);
    float2 w2 = cmul(w1, w1);
    float2 w3 = cmul(w2, w1);
    int i0 = k + 4 * jm;
    dst[i0]         = cadd(t0, t2);
    dst[i0 +     m] = cmul(w1, cadd(t1, t3));
    dst[i0 + 2 * m] = cmul(w2, csub(t0, t2));
    dst[i0 + 3 * m] = cmul(w3, csub(t1, t3));
    float2* tmp = src; src = dst; dst = tmp;
    m <<= 2;
  }
  // 4 stages: A->S->A->S->A, result back in A.
}

// Forward FFT along rows. 4 rows per workgroup (one per wave).
__global__ __launch_bounds__(256) void k_rowfft(const float* __restrict__ x,
    float2* __restrict__ wsimg, int img0, int img_step) {
  __shared__ float2 A[4][256];
  __shared__ float2 S[4][256];
  int wave = threadIdx.x >> 6, lane = threadIdx.x & 63;
  int slot = blockIdx.y;
  int img  = img0 + slot * img_step;
  int row  = blockIdx.x * 4 + wave;
  const float* xr = x + ((size_t)img << 16) + ((size_t)row << 8);
  #pragma unroll
  for (int q = 0; q < 4; ++q) {
    float v = xr[lane + 64 * q];
    A[wave][lane + 64 * q] = make_float2(v, 0.0f);
  }
  fft256<-1>(A[wave], S[wave], lane);
  float2* wr = wsimg + ((size_t)slot << 16) + ((size_t)row << 8);
  #pragma unroll
  for (int q = 0; q < 4; ++q) wr[lane + 64 * q] = A[wave][lane + 64 * q];
}

// Inverse FFT along rows + magnitude * 1/65536 -> out.
__global__ __launch_bounds__(256) void k_irowfft(const float2* __restrict__ wsimg,
    float* __restrict__ out, int img0, int img_step) {
  __shared__ float2 A[4][256];
  __shared__ float2 S[4][256];
  int wave = threadIdx.x >> 6, lane = threadIdx.x & 63;
  int slot = blockIdx.y;
  int img  = img0 + slot * img_step;
  int row  = blockIdx.x * 4 + wave;
  const float2* wr = wsimg + ((size_t)slot << 16) + ((size_t)row << 8);
  #pragma unroll
  for (int q = 0; q < 4; ++q) A[wave][lane + 64 * q] = wr[lane + 64 * q];
  fft256<1>(A[wave], S[wave], lane);
  float* orow = out + ((size_t)img << 16) + ((size_t)row << 8);
  #pragma unroll
  for (int q = 0; q < 4; ++q) {
    float2 v = A[wave][lane + 64 * q];
    orow[lane + 64 * q] = sqrtf(v.x * v.x + v.y * v.y) * (1.0f / 65536.0f);
  }
}

// Column pass over a 16-column tile. MODE 0: forward FFT + ring-energy
// histogram (double atomics). MODE 1: forward FFT + box mask + inverse FFT,
// written back in place.
template<int MODE>
__global__ __launch_bounds__(256) void k_colfft(float2* __restrict__ wsimg,
    double* __restrict__ bins, const int* __restrict__ cutoffs,
    int img0, int img_step) {
  __shared__ float2 T[16][257];   // padded: avoids 16-way transpose conflicts
  __shared__ float2 S[4][256];
  int tid = threadIdx.x, wave = tid >> 6, lane = tid & 63;
  int slot = blockIdx.y;
  int img  = img0 + slot * img_step;
  int colbase = blockIdx.x * 16;
  float2* base = wsimg + ((size_t)slot << 16);
  #pragma unroll
  for (int i = 0; i < 16; ++i) {
    int r = i * 16 + (tid >> 4);
    int c = tid & 15;
    T[c][r] = base[(r << 8) + colbase + c];
  }
  __syncthreads();
  int batch = img >> 6;
  int cut = (MODE == 1) ? cutoffs[batch] : 0;
  #pragma unroll 1
  for (int cc = 0; cc < 4; ++cc) {
    int c  = (wave << 2) + cc;
    int gc = colbase + c;
    fft256<-1>(&T[c][0], S[wave], lane);
    if (MODE == 0) {
      int fc = (gc < 128) ? gc + 1 : 256 - gc;
      #pragma unroll
      for (int q = 0; q < 4; ++q) {
        int u = lane + 64 * q;
        float2 v = T[c][u];
        int fu = (u < 128) ? u + 1 : 256 - u;
        int seg = fu > fc ? fu : fc;
        atomicAdd(&bins[batch * 129 + seg], (double)(v.x * v.x + v.y * v.y));
      }
    } else {
      bool cin = (gc < cut) || (gc >= 256 - cut);
      if (cin) {
        #pragma unroll
        for (int q = 0; q < 4; ++q) {
          int u = lane + 64 * q;
          if (u < cut || u >= 256 - cut) T[c][u] = make_float2(0.0f, 0.0f);
        }
      }
      fft256<1>(&T[c][0], S[wave], lane);
    }
  }
  if (MODE == 1) {
    __syncthreads();
    #pragma unroll
    for (int i = 0; i < 16; ++i) {
      int r = i * 16 + (tid >> 4);
      int c = tid & 15;
      base[(r << 8) + colbase + c] = T[c][r];
    }
  }
}

__global__ void k_cutoff(const double* __restrict__ bins, int* __restrict__ cutoffs) {
  int b = threadIdx.x;
  if (b < 8) {
    const double* Bv = bins + b * 129;
    double total = 0.0;
    for (int s = 0; s < 129; ++s) total += Bv[s];
    double target = 0.4 * total;
    double cum = Bv[0];
    int cut = 5;
    bool found = false;
    for (int s = 1; s <= 127; ++s) {
      cum += Bv[s];
      if (!found && cum >= target) { cut = s; found = true; }
    }
    cutoffs[b] = cut;
  }
}

extern "C" void kernel_launch(void* const* d_in, const int* in_sizes, int n_in,
                              void* d_out, int out_size, void* d_ws, size_t ws_size,
                              hipStream_t stream) {
  const float* x = (const float*)d_in[0];
  float* out = (float*)d_out;
  char* wsb = (char*)d_ws;
  double* bins   = (double*)wsb;             // 8*129 doubles = 8256 B
  int*    cutoffs = (int*)(wsb + 8448);
  float2* imgws  = (float2*)(wsb + RESERVE);

  size_t avail = (ws_size > RESERVE) ? ws_size - (size_t)RESERVE : 0;
  long long Gl = (long long)(avail / IMG_BYTES);
  int G = (Gl > 512) ? 512 : (int)Gl;
  if (G < 1) G = 1;

  hipMemsetAsync(bins, 0, 8 * 129 * sizeof(double), stream);
  dim3 blk(256, 1, 1);

  // Pre-pass: channel 0 of each batch (images b*64), histogram + cutoff.
  for (int b0 = 0; b0 < 8; b0 += G) {
    int n = (8 - b0 < G) ? (8 - b0) : G;
    k_rowfft<<<dim3(64, n), blk, 0, stream>>>(x, imgws, b0 * 64, 64);
    k_colfft<0><<<dim3(16, n), blk, 0, stream>>>(imgws, bins, nullptr, b0 * 64, 64);
  }
  k_cutoff<<<dim3(1), dim3(64), 0, stream>>>(bins, cutoffs);

  // Main pass: all 512 images, grouped by workspace capacity.
  for (int g0 = 0; g0 < 512; g0 += G) {
    int n = (512 - g0 < G) ? (512 - g0) : G;
    k_rowfft<<<dim3(64, n), blk, 0, stream>>>(x, imgws, g0, 1);
    k_colfft<1><<<dim3(16, n), blk, 0, stream>>>(imgws, nullptr, cutoffs, g0, 1);
    k_irowfft<<<dim3(64, n), blk, 0, stream>>>(imgws, out, g0, 1);
  }
}

// Round 2
// 338.491 us; speedup vs baseline: 1.2227x; 1.2227x over previous
//
#include <hip/hip_runtime.h>
#include <hip/hip_fp16.h>
#include <math.h>

#define RESERVE 16384

__device__ __forceinline__ float2 cadd(float2 a, float2 b){ return make_float2(a.x+b.x, a.y+b.y); }
__device__ __forceinline__ float2 csub(float2 a, float2 b){ return make_float2(a.x-b.x, a.y-b.y); }
__device__ __forceinline__ float2 cmul(float2 a, float2 b){ return make_float2(a.x*b.x - a.y*b.y, a.x*b.y + a.y*b.x); }
__device__ __forceinline__ float2 cmulc(float2 a, float2 b){ // conj(a)*b
  return make_float2(a.x*b.x + a.y*b.y, a.x*b.y - a.y*b.x); }
__device__ __forceinline__ __half2 f2h(float2 v){ return __floats2half2_rn(v.x, v.y); }
__device__ __forceinline__ float2 h2f(__half2 h){ return __half22float2(h); }

// Block compiler motion of DS ops across this point (allow ALU/VMEM).
#define SCHED_FENCE() __builtin_amdgcn_sched_barrier(0x7F)

// Forward twiddles for stages 0..2 (stage 3 twiddles are all 1).
// tw[3s+0]=w1, +1=w2, +2=w3 with w1 = exp(-i*pi*jm/128), jm = lane & ~(4^s-1).
__device__ __forceinline__ void make_tw(int lane, float2* tw) {
  #pragma unroll
  for (int s = 0; s < 3; ++s) {
    int jm = lane & ~((1 << (2*s)) - 1);
    float sw, cw;
    sincospif((float)jm * (-1.0f/128.0f), &sw, &cw);
    float2 w1 = make_float2(cw, sw);
    float2 w2 = cmul(w1, w1);
    tw[3*s] = w1; tw[3*s+1] = w2; tw[3*s+2] = cmul(w2, w1);
  }
}

// 256-pt radix-4 Stockham, one wave per FFT. Values live in registers at
// logical positions lane+64q; LDS buf (256 float2, XOR-swizzled) used for the
// 3 inter-stage permutations. phi(i) = i ^ (((i>>4)&3)<<2) ^ ((i>>6)&3)
// makes every stage's scatter-write and the linear read bank-conflict-free.
template<int DIR>
__device__ __forceinline__ void fft256r(float2& c0, float2& c1, float2& c2, float2& c3,
                                        float2* buf, int lane, const float2* tw) {
  const int pl = lane ^ (((lane >> 4) & 3) << 2);  // phi(lane); lane<64 so no b6b7 term
  #pragma unroll
  for (int s = 0; s < 4; ++s) {
    float2 t0 = cadd(c0, c2), t1 = csub(c0, c2), t2 = cadd(c1, c3), d = csub(c1, c3);
    float2 t3 = (DIR < 0) ? make_float2(d.y, -d.x) : make_float2(-d.y, d.x);
    float2 o0 = cadd(t0, t2), o1 = cadd(t1, t3), o2 = csub(t0, t2), o3 = csub(t1, t3);
    if (s < 3) {
      float2 w1 = tw[3*s], w2 = tw[3*s+1], w3 = tw[3*s+2];
      if (DIR < 0) { o1 = cmul(w1, o1);  o2 = cmul(w2, o2);  o3 = cmul(w3, o3); }
      else         { o1 = cmulc(w1, o1); o2 = cmulc(w2, o2); o3 = cmulc(w3, o3); }
      const int m = 1 << (2*s);
      const int j = lane >> (2*s);
      const int i0 = (lane & (m - 1)) + (j << (2*s + 2));   // k + 4*j*m
      const int pb = i0 ^ (((i0 >> 4) & 3) << 2) ^ ((i0 >> 6) & 3);
      // phi(i0 + t*m) = pb ^ (t<<2s) ^ (s==2 ? t<<2 : 0)  (t occupies clean bits)
      buf[pb] = o0;
      buf[pb ^ (1 << (2*s)) ^ ((s == 2) ? 4 : 0)]  = o1;
      buf[pb ^ (2 << (2*s)) ^ ((s == 2) ? 8 : 0)]  = o2;
      buf[pb ^ (3 << (2*s)) ^ ((s == 2) ? 12 : 0)] = o3;
      SCHED_FENCE();
      c0 = buf[pl];
      c1 = buf[pl ^ 64 ^ 1];
      c2 = buf[pl ^ 128 ^ 2];
      c3 = buf[pl ^ 192 ^ 3];
      SCHED_FENCE();
    } else { c0 = o0; c1 = o1; c2 = o2; c3 = o3; }
  }
}

// ---------- Pass 1: row FFT (fp32 in) -> Bt[v][r] fp16, transposed ----------
__global__ __launch_bounds__(256) void k_pass1(const float* __restrict__ x,
    __half2* __restrict__ Bt, int img0) {
  __shared__ float2 fbuf[4][256];
  __shared__ __half2 tile[256][17];   // [v][r_local], pad 17 -> conflict-free
  const int tid = threadIdx.x, wave = tid >> 6, lane = tid & 63;
  const int slot = blockIdx.y, img = img0 + slot;
  const int r0 = blockIdx.x << 4;
  float2 tw[9]; make_tw(lane, tw);
  const float* xim = x + ((size_t)img << 16);
  #pragma unroll 1
  for (int i = 0; i < 4; ++i) {
    const int rl = (wave << 2) + i;
    const float* xr = xim + ((size_t)(r0 + rl) << 8);
    float2 c0 = make_float2(xr[lane],        0.f);
    float2 c1 = make_float2(xr[lane + 64],   0.f);
    float2 c2 = make_float2(xr[lane + 128],  0.f);
    float2 c3 = make_float2(xr[lane + 192],  0.f);
    fft256r<-1>(c0, c1, c2, c3, fbuf[wave], lane, tw);
    tile[lane      ][rl] = f2h(c0);
    tile[lane + 64 ][rl] = f2h(c1);
    tile[lane + 128][rl] = f2h(c2);
    tile[lane + 192][rl] = f2h(c3);
  }
  __syncthreads();
  __half2* bo = Bt + ((size_t)slot << 16) + r0;
  const int rr = tid & 15, vb = tid >> 4;
  #pragma unroll
  for (int j = 0; j < 16; ++j) {
    int v = (j << 4) + vb;
    bo[((size_t)v << 8) + rr] = tile[v][rr];
  }
}

// ------ Pass 2: col FFT + highpass mask + col IFFT; Bt -> C[r][v] fp16 ------
__global__ __launch_bounds__(256) void k_pass2(const __half2* __restrict__ Bt,
    __half2* __restrict__ Ct, const int* __restrict__ cutoffs, int img0) {
  __shared__ float2 fbuf[4][256];
  __shared__ __half2 tile[256][17];   // [r][c_local]
  const int tid = threadIdx.x, wave = tid >> 6, lane = tid & 63;
  const int slot = blockIdx.y, img = img0 + slot;
  const int v0 = blockIdx.x << 4;
  const int cut = cutoffs[img >> 6];  // 1..127
  float2 tw[9]; make_tw(lane, tw);
  const __half2* bi = Bt + ((size_t)slot << 16);
  #pragma unroll 1
  for (int i = 0; i < 4; ++i) {
    const int cl = (wave << 2) + i;
    const int v = v0 + cl;
    const __half2* col = bi + ((size_t)v << 8);
    float2 c0 = h2f(col[lane]);
    float2 c1 = h2f(col[lane + 64]);
    float2 c2 = h2f(col[lane + 128]);
    float2 c3 = h2f(col[lane + 192]);
    fft256r<-1>(c0, c1, c2, c3, fbuf[wave], lane, tw);
    if ((v < cut) || (v >= 256 - cut)) {
      // zero F(u,v) where u in the cut box; u = lane+64q, cut<=127
      if (lane < cut)               c0 = make_float2(0.f, 0.f);
      if (lane + 64 < cut)          c1 = make_float2(0.f, 0.f);
      if (lane + 128 >= 256 - cut)  c2 = make_float2(0.f, 0.f);
      if (lane + 192 >= 256 - cut)  c3 = make_float2(0.f, 0.f);
    }
    fft256r<1>(c0, c1, c2, c3, fbuf[wave], lane, tw);
    tile[lane      ][cl] = f2h(c0);
    tile[lane + 64 ][cl] = f2h(c1);
    tile[lane + 128][cl] = f2h(c2);
    tile[lane + 192][cl] = f2h(c3);
  }
  __syncthreads();
  __half2* co = Ct + ((size_t)slot << 16) + v0;
  const int cc = tid & 15, rb = tid >> 4;
  #pragma unroll
  for (int j = 0; j < 16; ++j) {
    int r = (j << 4) + rb;
    co[((size_t)r << 8) + cc] = tile[r][cc];
  }
}

// ---------- Pass 3: row IFFT + |.|/65536 -> out ----------
__global__ __launch_bounds__(256) void k_pass3(const __half2* __restrict__ Ct,
    float* __restrict__ out, int img0) {
  __shared__ float2 fbuf[4][256];
  const int tid = threadIdx.x, wave = tid >> 6, lane = tid & 63;
  const int slot = blockIdx.y, img = img0 + slot;
  const int r0 = blockIdx.x << 4;
  float2 tw[9]; make_tw(lane, tw);
  const __half2* cim = Ct + ((size_t)slot << 16);
  float* oim = out + ((size_t)img << 16);
  #pragma unroll 1
  for (int i = 0; i < 4; ++i) {
    const int r = r0 + (wave << 2) + i;
    const __half2* row = cim + ((size_t)r << 8);
    float2 c0 = h2f(row[lane]);
    float2 c1 = h2f(row[lane + 64]);
    float2 c2 = h2f(row[lane + 128]);
    float2 c3 = h2f(row[lane + 192]);
    fft256r<1>(c0, c1, c2, c3, fbuf[wave], lane, tw);
    float* orow = oim + ((size_t)r << 8);
    orow[lane]       = sqrtf(c0.x*c0.x + c0.y*c0.y) * (1.f/65536.f);
    orow[lane + 64]  = sqrtf(c1.x*c1.x + c1.y*c1.y) * (1.f/65536.f);
    orow[lane + 128] = sqrtf(c2.x*c2.x + c2.y*c2.y) * (1.f/65536.f);
    orow[lane + 192] = sqrtf(c3.x*c3.x + c3.y*c3.y) * (1.f/65536.f);
  }
}

// =================== fp32 pre-pass (verified round-1 code) ===================
template<int DIR>
__device__ __forceinline__ void fft256_ps(float2* A, float2* S, int lane) {
  float2* src = A;
  float2* dst = S;
  int m = 1;
  #pragma unroll
  for (int s = 0; s < 4; ++s) {
    int j  = lane / m;
    int k  = lane - j * m;
    int jm = j * m;
    float2 c0 = src[lane];
    float2 c1 = src[lane + 64];
    float2 c2 = src[lane + 128];
    float2 c3 = src[lane + 192];
    float2 t0 = cadd(c0, c2);
    float2 t1 = csub(c0, c2);
    float2 t2 = cadd(c1, c3);
    float2 d  = csub(c1, c3);
    float2 t3 = (DIR < 0) ? make_float2(d.y, -d.x) : make_float2(-d.y, d.x);
    float a = (float)DIR * (float)jm * (1.0f / 128.0f);
    float sw, cw;
    sincospif(a, &sw, &cw);
    float2 w1 = make_float2(cw, sw);
    float2 w2 = cmul(w1, w1);
    float2 w3 = cmul(w2, w1);
    int i0 = k + 4 * jm;
    dst[i0]         = cadd(t0, t2);
    dst[i0 +     m] = cmul(w1, cadd(t1, t3));
    dst[i0 + 2 * m] = cmul(w2, csub(t0, t2));
    dst[i0 + 3 * m] = cmul(w3, csub(t1, t3));
    float2* tmp = src; src = dst; dst = tmp;
    m <<= 2;
  }
}

__global__ __launch_bounds__(256) void k_rowfft_f32(const float* __restrict__ x,
    float2* __restrict__ wsimg, int img0, int img_step) {
  __shared__ float2 A[4][256];
  __shared__ float2 S[4][256];
  int wave = threadIdx.x >> 6, lane = threadIdx.x & 63;
  int slot = blockIdx.y;
  int img  = img0 + slot * img_step;
  int row  = blockIdx.x * 4 + wave;
  const float* xr = x + ((size_t)img << 16) + ((size_t)row << 8);
  #pragma unroll
  for (int q = 0; q < 4; ++q) {
    float v = xr[lane + 64 * q];
    A[wave][lane + 64 * q] = make_float2(v, 0.0f);
  }
  fft256_ps<-1>(A[wave], S[wave], lane);
  float2* wr = wsimg + ((size_t)slot << 16) + ((size_t)row << 8);
  #pragma unroll
  for (int q = 0; q < 4; ++q) wr[lane + 64 * q] = A[wave][lane + 64 * q];
}

__global__ __launch_bounds__(256) void k_colhist(float2* __restrict__ wsimg,
    double* __restrict__ bins, int img0, int img_step) {
  __shared__ float2 T[16][257];
  __shared__ float2 S[4][256];
  int tid = threadIdx.x, wave = tid >> 6, lane = tid & 63;
  int slot = blockIdx.y;
  int img  = img0 + slot * img_step;
  int colbase = blockIdx.x * 16;
  float2* base = wsimg + ((size_t)slot << 16);
  #pragma unroll
  for (int i = 0; i < 16; ++i) {
    int r = i * 16 + (tid >> 4);
    int c = tid & 15;
    T[c][r] = base[(r << 8) + colbase + c];
  }
  __syncthreads();
  int batch = img >> 6;
  #pragma unroll 1
  for (int cc = 0; cc < 4; ++cc) {
    int c  = (wave << 2) + cc;
    int gc = colbase + c;
    fft256_ps<-1>(&T[c][0], S[wave], lane);
    int fc = (gc < 128) ? gc + 1 : 256 - gc;
    #pragma unroll
    for (int q = 0; q < 4; ++q) {
      int u = lane + 64 * q;
      float2 v = T[c][u];
      int fu = (u < 128) ? u + 1 : 256 - u;
      int seg = fu > fc ? fu : fc;
      atomicAdd(&bins[batch * 129 + seg], (double)(v.x * v.x + v.y * v.y));
    }
  }
}

__global__ void k_cutoff(const double* __restrict__ bins, int* __restrict__ cutoffs) {
  int b = threadIdx.x;
  if (b < 8) {
    const double* Bv = bins + b * 129;
    double total = 0.0;
    for (int s = 0; s < 129; ++s) total += Bv[s];
    double target = 0.4 * total;
    double cum = Bv[0];
    int cut = 5;
    bool found = false;
    for (int s = 1; s <= 127; ++s) {
      cum += Bv[s];
      if (!found && cum >= target) { cut = s; found = true; }
    }
    cutoffs[b] = cut;
  }
}

extern "C" void kernel_launch(void* const* d_in, const int* in_sizes, int n_in,
                              void* d_out, int out_size, void* d_ws, size_t ws_size,
                              hipStream_t stream) {
  const float* x = (const float*)d_in[0];
  float* out = (float*)d_out;
  char* wsb = (char*)d_ws;
  double* bins   = (double*)wsb;           // 8*129 doubles
  int*    cutoffs = (int*)(wsb + 8448);
  char*   payload = wsb + RESERVE;

  size_t avail = (ws_size > RESERVE) ? ws_size - (size_t)RESERVE : 0;
  // Per image: 256KB Bt (fp16) + 256KB Ct (fp16) = 512KB; prepass fp32 needs
  // 512KB/image too (aliases payload; runs before main pass).
  long long Gl = (long long)(avail / 524288);
  int G = (Gl > 512) ? 512 : (int)Gl;
  if (G < 1) G = 1;
  __half2* Bt = (__half2*)payload;
  __half2* Ct = (__half2*)(payload + (size_t)G * 262144);
  float2*  f32ws = (float2*)payload;

  hipMemsetAsync(bins, 0, 8 * 129 * sizeof(double), stream);
  dim3 blk(256, 1, 1);

  // Pre-pass: channel 0 of each batch -> fp32 spectrum -> ring histogram.
  int Gp = G > 8 ? 8 : G;
  for (int b0 = 0; b0 < 8; b0 += Gp) {
    int n = (8 - b0 < Gp) ? (8 - b0) : Gp;
    k_rowfft_f32<<<dim3(64, n), blk, 0, stream>>>(x, f32ws, b0 * 64, 64);
    k_colhist<<<dim3(16, n), blk, 0, stream>>>(f32ws, bins, b0 * 64, 64);
  }
  k_cutoff<<<dim3(1), dim3(64), 0, stream>>>(bins, cutoffs);

  // Main pass: all 512 images.
  for (int g0 = 0; g0 < 512; g0 += G) {
    int n = (512 - g0 < G) ? (512 - g0) : G;
    k_pass1<<<dim3(16, n), blk, 0, stream>>>(x, Bt, g0);
    k_pass2<<<dim3(16, n), blk, 0, stream>>>(Bt, Ct, cutoffs, g0);
    k_pass3<<<dim3(16, n), blk, 0, stream>>>(Ct, out, g0);
  }
}

// Round 3
// 256.876 us; speedup vs baseline: 1.6112x; 1.3177x over previous
//
#include <hip/hip_runtime.h>
#include <hip/hip_fp16.h>
#include <math.h>

#define RESERVE 16384

__device__ __forceinline__ float2 cadd(float2 a, float2 b){ return make_float2(a.x+b.x, a.y+b.y); }
__device__ __forceinline__ float2 csub(float2 a, float2 b){ return make_float2(a.x-b.x, a.y-b.y); }
__device__ __forceinline__ float2 cmul(float2 a, float2 b){ return make_float2(a.x*b.x - a.y*b.y, a.x*b.y + a.y*b.x); }
__device__ __forceinline__ float2 cmulc(float2 a, float2 b){ // conj(a)*b
  return make_float2(a.x*b.x + a.y*b.y, a.x*b.y - a.y*b.x); }
__device__ __forceinline__ __half2 f2h(float2 v){ return __floats2half2_rn(v.x, v.y); }
__device__ __forceinline__ float2 h2f(__half2 h){ return __half22float2(h); }

// Block compiler motion of DS ops across this point (allow ALU/VMEM).
#define SCHED_FENCE() __builtin_amdgcn_sched_barrier(0x7F)

// Forward twiddles for stages 0..2 (stage 3 twiddles are all 1).
// tw[3s+0]=w1, +1=w2, +2=w3 with w1 = exp(-i*pi*jm/128), jm = lane & ~(4^s-1).
__device__ __forceinline__ void make_tw(int lane, float2* tw) {
  #pragma unroll
  for (int s = 0; s < 3; ++s) {
    int jm = lane & ~((1 << (2*s)) - 1);
    float sw, cw;
    sincospif((float)jm * (-1.0f/128.0f), &sw, &cw);
    float2 w1 = make_float2(cw, sw);
    float2 w2 = cmul(w1, w1);
    tw[3*s] = w1; tw[3*s+1] = w2; tw[3*s+2] = cmul(w2, w1);
  }
}

// 256-pt radix-4 Stockham, one wave per FFT. Values live in registers at
// logical positions lane+64q; LDS buf (256 float2, XOR-swizzled) used for the
// 3 inter-stage permutations. phi(i) = i ^ (((i>>4)&3)<<2) ^ ((i>>6)&3)
// makes every stage's scatter-write and the linear read bank-conflict-free.
template<int DIR>
__device__ __forceinline__ void fft256r(float2& c0, float2& c1, float2& c2, float2& c3,
                                        float2* buf, int lane, const float2* tw) {
  const int pl = lane ^ (((lane >> 4) & 3) << 2);  // phi(lane); lane<64 so no b6b7 term
  #pragma unroll
  for (int s = 0; s < 4; ++s) {
    float2 t0 = cadd(c0, c2), t1 = csub(c0, c2), t2 = cadd(c1, c3), d = csub(c1, c3);
    float2 t3 = (DIR < 0) ? make_float2(d.y, -d.x) : make_float2(-d.y, d.x);
    float2 o0 = cadd(t0, t2), o1 = cadd(t1, t3), o2 = csub(t0, t2), o3 = csub(t1, t3);
    if (s < 3) {
      float2 w1 = tw[3*s], w2 = tw[3*s+1], w3 = tw[3*s+2];
      if (DIR < 0) { o1 = cmul(w1, o1);  o2 = cmul(w2, o2);  o3 = cmul(w3, o3); }
      else         { o1 = cmulc(w1, o1); o2 = cmulc(w2, o2); o3 = cmulc(w3, o3); }
      const int m = 1 << (2*s);
      const int j = lane >> (2*s);
      const int i0 = (lane & (m - 1)) + (j << (2*s + 2));   // k + 4*j*m
      const int pb = i0 ^ (((i0 >> 4) & 3) << 2) ^ ((i0 >> 6) & 3);
      // phi(i0 + t*m) = pb ^ (t<<2s) ^ (s==2 ? t<<2 : 0)  (t occupies clean bits)
      buf[pb] = o0;
      buf[pb ^ (1 << (2*s)) ^ ((s == 2) ? 4 : 0)]  = o1;
      buf[pb ^ (2 << (2*s)) ^ ((s == 2) ? 8 : 0)]  = o2;
      buf[pb ^ (3 << (2*s)) ^ ((s == 2) ? 12 : 0)] = o3;
      SCHED_FENCE();
      c0 = buf[pl];
      c1 = buf[pl ^ 64 ^ 1];
      c2 = buf[pl ^ 128 ^ 2];
      c3 = buf[pl ^ 192 ^ 3];
      SCHED_FENCE();
    } else { c0 = o0; c1 = o1; c2 = o2; c3 = o3; }
  }
}

// ---------- Pass 1: row FFT (fp32 in) -> Bt[v][r] fp16, transposed ----------
__global__ __launch_bounds__(256) void k_pass1(const float* __restrict__ x,
    __half2* __restrict__ Bt, int img0) {
  __shared__ float2 fbuf[4][256];
  __shared__ __half2 tile[256][17];   // [v][r_local], pad 17 -> conflict-free
  const int tid = threadIdx.x, wave = tid >> 6, lane = tid & 63;
  const int slot = blockIdx.y, img = img0 + slot;
  const int r0 = blockIdx.x << 4;
  float2 tw[9]; make_tw(lane, tw);
  const float* xim = x + ((size_t)img << 16);
  #pragma unroll 1
  for (int i = 0; i < 4; ++i) {
    const int rl = (wave << 2) + i;
    const float* xr = xim + ((size_t)(r0 + rl) << 8);
    float2 c0 = make_float2(xr[lane],        0.f);
    float2 c1 = make_float2(xr[lane + 64],   0.f);
    float2 c2 = make_float2(xr[lane + 128],  0.f);
    float2 c3 = make_float2(xr[lane + 192],  0.f);
    fft256r<-1>(c0, c1, c2, c3, fbuf[wave], lane, tw);
    tile[lane      ][rl] = f2h(c0);
    tile[lane + 64 ][rl] = f2h(c1);
    tile[lane + 128][rl] = f2h(c2);
    tile[lane + 192][rl] = f2h(c3);
  }
  __syncthreads();
  __half2* bo = Bt + ((size_t)slot << 16) + r0;
  const int rr = tid & 15, vb = tid >> 4;
  #pragma unroll
  for (int j = 0; j < 16; ++j) {
    int v = (j << 4) + vb;
    bo[((size_t)v << 8) + rr] = tile[v][rr];
  }
}

// ------ Pass 2: col FFT + highpass mask + col IFFT; Bt -> C[r][v] fp16 ------
__global__ __launch_bounds__(256) void k_pass2(const __half2* __restrict__ Bt,
    __half2* __restrict__ Ct, const int* __restrict__ cutoffs, int img0) {
  __shared__ float2 fbuf[4][256];
  __shared__ __half2 tile[256][17];   // [r][c_local]
  const int tid = threadIdx.x, wave = tid >> 6, lane = tid & 63;
  const int slot = blockIdx.y, img = img0 + slot;
  const int v0 = blockIdx.x << 4;
  const int cut = cutoffs[img >> 6];  // 1..127
  float2 tw[9]; make_tw(lane, tw);
  const __half2* bi = Bt + ((size_t)slot << 16);
  #pragma unroll 1
  for (int i = 0; i < 4; ++i) {
    const int cl = (wave << 2) + i;
    const int v = v0 + cl;
    const __half2* col = bi + ((size_t)v << 8);
    float2 c0 = h2f(col[lane]);
    float2 c1 = h2f(col[lane + 64]);
    float2 c2 = h2f(col[lane + 128]);
    float2 c3 = h2f(col[lane + 192]);
    fft256r<-1>(c0, c1, c2, c3, fbuf[wave], lane, tw);
    if ((v < cut) || (v >= 256 - cut)) {
      // zero F(u,v) where u in the cut box; u = lane+64q, cut<=127
      if (lane < cut)               c0 = make_float2(0.f, 0.f);
      if (lane + 64 < cut)          c1 = make_float2(0.f, 0.f);
      if (lane + 128 >= 256 - cut)  c2 = make_float2(0.f, 0.f);
      if (lane + 192 >= 256 - cut)  c3 = make_float2(0.f, 0.f);
    }
    fft256r<1>(c0, c1, c2, c3, fbuf[wave], lane, tw);
    tile[lane      ][cl] = f2h(c0);
    tile[lane + 64 ][cl] = f2h(c1);
    tile[lane + 128][cl] = f2h(c2);
    tile[lane + 192][cl] = f2h(c3);
  }
  __syncthreads();
  __half2* co = Ct + ((size_t)slot << 16) + v0;
  const int cc = tid & 15, rb = tid >> 4;
  #pragma unroll
  for (int j = 0; j < 16; ++j) {
    int r = (j << 4) + rb;
    co[((size_t)r << 8) + cc] = tile[r][cc];
  }
}

// ---------- Pass 3: row IFFT + |.|/65536 -> out ----------
__global__ __launch_bounds__(256) void k_pass3(const __half2* __restrict__ Ct,
    float* __restrict__ out, int img0) {
  __shared__ float2 fbuf[4][256];
  const int tid = threadIdx.x, wave = tid >> 6, lane = tid & 63;
  const int slot = blockIdx.y, img = img0 + slot;
  const int r0 = blockIdx.x << 4;
  float2 tw[9]; make_tw(lane, tw);
  const __half2* cim = Ct + ((size_t)slot << 16);
  float* oim = out + ((size_t)img << 16);
  #pragma unroll 1
  for (int i = 0; i < 4; ++i) {
    const int r = r0 + (wave << 2) + i;
    const __half2* row = cim + ((size_t)r << 8);
    float2 c0 = h2f(row[lane]);
    float2 c1 = h2f(row[lane + 64]);
    float2 c2 = h2f(row[lane + 128]);
    float2 c3 = h2f(row[lane + 192]);
    fft256r<1>(c0, c1, c2, c3, fbuf[wave], lane, tw);
    float* orow = oim + ((size_t)r << 8);
    orow[lane]       = sqrtf(c0.x*c0.x + c0.y*c0.y) * (1.f/65536.f);
    orow[lane + 64]  = sqrtf(c1.x*c1.x + c1.y*c1.y) * (1.f/65536.f);
    orow[lane + 128] = sqrtf(c2.x*c2.x + c2.y*c2.y) * (1.f/65536.f);
    orow[lane + 192] = sqrtf(c3.x*c3.x + c3.y*c3.y) * (1.f/65536.f);
  }
}

// =================== fp32 pre-pass (histogram + cutoff) ===================
template<int DIR>
__device__ __forceinline__ void fft256_ps(float2* A, float2* S, int lane) {
  float2* src = A;
  float2* dst = S;
  int m = 1;
  #pragma unroll
  for (int s = 0; s < 4; ++s) {
    int j  = lane / m;
    int k  = lane - j * m;
    int jm = j * m;
    float2 c0 = src[lane];
    float2 c1 = src[lane + 64];
    float2 c2 = src[lane + 128];
    float2 c3 = src[lane + 192];
    float2 t0 = cadd(c0, c2);
    float2 t1 = csub(c0, c2);
    float2 t2 = cadd(c1, c3);
    float2 d  = csub(c1, c3);
    float2 t3 = (DIR < 0) ? make_float2(d.y, -d.x) : make_float2(-d.y, d.x);
    float a = (float)DIR * (float)jm * (1.0f / 128.0f);
    float sw, cw;
    sincospif(a, &sw, &cw);
    float2 w1 = make_float2(cw, sw);
    float2 w2 = cmul(w1, w1);
    float2 w3 = cmul(w2, w1);
    int i0 = k + 4 * jm;
    dst[i0]         = cadd(t0, t2);
    dst[i0 +     m] = cmul(w1, cadd(t1, t3));
    dst[i0 + 2 * m] = cmul(w2, csub(t0, t2));
    dst[i0 + 3 * m] = cmul(w3, csub(t1, t3));
    float2* tmp = src; src = dst; dst = tmp;
    m <<= 2;
  }
}

__global__ __launch_bounds__(256) void k_rowfft_f32(const float* __restrict__ x,
    float2* __restrict__ wsimg, int img0, int img_step) {
  __shared__ float2 A[4][256];
  __shared__ float2 S[4][256];
  int wave = threadIdx.x >> 6, lane = threadIdx.x & 63;
  int slot = blockIdx.y;
  int img  = img0 + slot * img_step;
  int row  = blockIdx.x * 4 + wave;
  const float* xr = x + ((size_t)img << 16) + ((size_t)row << 8);
  #pragma unroll
  for (int q = 0; q < 4; ++q) {
    float v = xr[lane + 64 * q];
    A[wave][lane + 64 * q] = make_float2(v, 0.0f);
  }
  fft256_ps<-1>(A[wave], S[wave], lane);
  float2* wr = wsimg + ((size_t)slot << 16) + ((size_t)row << 8);
  #pragma unroll
  for (int q = 0; q < 4; ++q) wr[lane + 64 * q] = A[wave][lane + 64 * q];
}

// Column FFT + hierarchical ring-energy histogram:
// per-wave LDS float bins -> per-block merge -> 129 global double atomics.
__global__ __launch_bounds__(256) void k_colhist(float2* __restrict__ wsimg,
    double* __restrict__ bins, int img0, int img_step) {
  __shared__ float2 T[16][257];
  __shared__ float2 S[4][256];
  __shared__ float whist[4][132];
  int tid = threadIdx.x, wave = tid >> 6, lane = tid & 63;
  int slot = blockIdx.y;
  int img  = img0 + slot * img_step;
  int colbase = blockIdx.x * 16;
  float2* base = wsimg + ((size_t)slot << 16);
  #pragma unroll
  for (int i = 0; i < 16; ++i) {
    int r = i * 16 + (tid >> 4);
    int c = tid & 15;
    T[c][r] = base[(r << 8) + colbase + c];
  }
  #pragma unroll
  for (int i = lane; i < 132; i += 64) whist[wave][i] = 0.0f;
  __syncthreads();
  int batch = img >> 6;
  #pragma unroll 1
  for (int cc = 0; cc < 4; ++cc) {
    int c  = (wave << 2) + cc;
    int gc = colbase + c;
    fft256_ps<-1>(&T[c][0], S[wave], lane);
    int fc = (gc < 128) ? gc + 1 : 256 - gc;
    // lane's 4 values at u = lane, lane+64, lane+128, lane+192 have rings:
    int fu0 = lane + 1, fu1 = lane + 65, fu2 = 128 - lane, fu3 = 64 - lane;
    float2 v0 = T[c][lane], v1 = T[c][lane+64], v2 = T[c][lane+128], v3 = T[c][lane+192];
    float m0 = v0.x*v0.x + v0.y*v0.y;
    float m1 = v1.x*v1.x + v1.y*v1.y;
    float m2 = v2.x*v2.x + v2.y*v2.y;
    float m3 = v3.x*v3.x + v3.y*v3.y;
    // seg = max(fu, fc): fu<=fc collapses to bin fc (wave-reduced), else bin fu.
    float box = 0.0f;
    if (fu0 <= fc) box += m0; else atomicAdd(&whist[wave][fu0], m0);
    if (fu1 <= fc) box += m1; else atomicAdd(&whist[wave][fu1], m1);
    if (fu2 <= fc) box += m2; else atomicAdd(&whist[wave][fu2], m2);
    if (fu3 <= fc) box += m3; else atomicAdd(&whist[wave][fu3], m3);
    #pragma unroll
    for (int msk = 1; msk < 64; msk <<= 1) box += __shfl_xor(box, msk, 64);
    if (lane == 0) atomicAdd(&whist[wave][fc], box);
  }
  __syncthreads();
  for (int s = tid; s < 129; s += 256) {
    float sum = whist[0][s] + whist[1][s] + whist[2][s] + whist[3][s];
    if (sum != 0.0f) atomicAdd(&bins[batch * 129 + s], (double)sum);
  }
}

__global__ void k_cutoff(const double* __restrict__ bins, int* __restrict__ cutoffs) {
  int b = threadIdx.x;
  if (b < 8) {
    const double* Bv = bins + b * 129;
    double total = 0.0;
    for (int s = 0; s < 129; ++s) total += Bv[s];
    double target = 0.4 * total;
    double cum = Bv[0];
    int cut = 5;
    bool found = false;
    for (int s = 1; s <= 127; ++s) {
      cum += Bv[s];
      if (!found && cum >= target) { cut = s; found = true; }
    }
    cutoffs[b] = cut;
  }
}

extern "C" void kernel_launch(void* const* d_in, const int* in_sizes, int n_in,
                              void* d_out, int out_size, void* d_ws, size_t ws_size,
                              hipStream_t stream) {
  const float* x = (const float*)d_in[0];
  float* out = (float*)d_out;
  char* wsb = (char*)d_ws;
  double* bins   = (double*)wsb;           // 8*129 doubles
  int*    cutoffs = (int*)(wsb + 8448);
  char*   payload = wsb + RESERVE;

  size_t avail = (ws_size > RESERVE) ? ws_size - (size_t)RESERVE : 0;
  // Per image: 256KB Bt (fp16) + 256KB Ct (fp16) = 512KB; prepass fp32 needs
  // 512KB/image too (aliases payload; runs before main pass).
  long long Gl = (long long)(avail / 524288);
  int G = (Gl > 512) ? 512 : (int)Gl;
  if (G < 1) G = 1;
  __half2* Bt = (__half2*)payload;
  __half2* Ct = (__half2*)(payload + (size_t)G * 262144);
  float2*  f32ws = (float2*)payload;

  hipMemsetAsync(bins, 0, 8 * 129 * sizeof(double), stream);
  dim3 blk(256, 1, 1);

  // Pre-pass: channel 0 of each batch -> fp32 spectrum -> ring histogram.
  int Gp = G > 8 ? 8 : G;
  for (int b0 = 0; b0 < 8; b0 += Gp) {
    int n = (8 - b0 < Gp) ? (8 - b0) : Gp;
    k_rowfft_f32<<<dim3(64, n), blk, 0, stream>>>(x, f32ws, b0 * 64, 64);
    k_colhist<<<dim3(16, n), blk, 0, stream>>>(f32ws, bins, b0 * 64, 64);
  }
  k_cutoff<<<dim3(1), dim3(64), 0, stream>>>(bins, cutoffs);

  // Main pass: all 512 images.
  for (int g0 = 0; g0 < 512; g0 += G) {
    int n = (512 - g0 < G) ? (512 - g0) : G;
    k_pass1<<<dim3(16, n), blk, 0, stream>>>(x, Bt, g0);
    k_pass2<<<dim3(16, n), blk, 0, stream>>>(Bt, Ct, cutoffs, g0);
    k_pass3<<<dim3(16, n), blk, 0, stream>>>(Ct, out, g0);
  }
}

// Round 4
// 250.612 us; speedup vs baseline: 1.6515x; 1.0250x over previous
//
#include <hip/hip_runtime.h>
#include <hip/hip_fp16.h>
#include <math.h>

#define RESERVE 16384

__device__ __forceinline__ float2 cadd(float2 a, float2 b){ return make_float2(a.x+b.x, a.y+b.y); }
__device__ __forceinline__ float2 csub(float2 a, float2 b){ return make_float2(a.x-b.x, a.y-b.y); }
__device__ __forceinline__ float2 cmul(float2 a, float2 b){ return make_float2(a.x*b.x - a.y*b.y, a.x*b.y + a.y*b.x); }
__device__ __forceinline__ float2 cmulc(float2 a, float2 b){ // conj(a)*b
  return make_float2(a.x*b.x + a.y*b.y, a.x*b.y - a.y*b.x); }
__device__ __forceinline__ __half2 f2h(float2 v){ return __floats2half2_rn(v.x, v.y); }
__device__ __forceinline__ float2 h2f(__half2 h){ return __half22float2(h); }

// Block compiler motion of DS ops across this point (ALU/VMEM may cross).
#define SCHED_FENCE() __builtin_amdgcn_sched_barrier(0x7F)

__device__ __forceinline__ constexpr int rho4(int r) { return ((r & 3) << 2) | (r >> 2); }

// multiply by forward constant (c,s); inverse uses conjugate
template<int DIR> __device__ __forceinline__ float2 twc(float2 z, float c, float s) {
  const float si = (DIR < 0) ? s : -s;
  return make_float2(c*z.x - si*z.y, c*z.y + si*z.x);
}
// multiply by W16^4 = -i (fwd) / +i (inv)
template<int DIR> __device__ __forceinline__ float2 mulmi(float2 z) {
  return (DIR < 0) ? make_float2(z.y, -z.x) : make_float2(-z.y, z.x);
}

// FFT-16 on 16 register-resident complex values, constant twiddles.
// REV=false: input x[j] at physical reg j; output X[k] at physical reg rho4(k).
// REV=true : input x[j] at physical reg rho4(j); output X[k] at physical reg k.
template<int DIR, bool REV>
__device__ __forceinline__ void fft16(float2* v) {
  #define IX(i) (REV ? rho4(i) : (i))
  // Stage 1: DFT-4 over stride-4 quads (j0 fixed)
  #pragma unroll
  for (int j0 = 0; j0 < 4; ++j0) {
    float2 a0 = v[IX(j0)], a1 = v[IX(j0+4)], a2 = v[IX(j0+8)], a3 = v[IX(j0+12)];
    float2 t0 = cadd(a0,a2), t1 = csub(a0,a2), t2 = cadd(a1,a3), d = csub(a1,a3);
    float2 t3 = (DIR < 0) ? make_float2(d.y,-d.x) : make_float2(-d.y,d.x);
    v[IX(j0)]    = cadd(t0,t2);
    v[IX(j0+4)]  = cadd(t1,t3);
    v[IX(j0+8)]  = csub(t0,t2);
    v[IX(j0+12)] = csub(t1,t3);
  }
  // Twiddle W16^{j0*k1} on logical reg r = j0 + 4*k1
  v[IX(5)]  = twc<DIR>(v[IX(5)],  0.92387953f, -0.38268343f);  // W^1
  v[IX(6)]  = twc<DIR>(v[IX(6)],  0.70710678f, -0.70710678f);  // W^2
  v[IX(7)]  = twc<DIR>(v[IX(7)],  0.38268343f, -0.92387953f);  // W^3
  v[IX(9)]  = twc<DIR>(v[IX(9)],  0.70710678f, -0.70710678f);  // W^2
  v[IX(10)] = mulmi<DIR>(v[IX(10)]);                            // W^4
  v[IX(11)] = twc<DIR>(v[IX(11)], -0.70710678f, -0.70710678f); // W^6
  v[IX(13)] = twc<DIR>(v[IX(13)],  0.38268343f, -0.92387953f); // W^3
  v[IX(14)] = twc<DIR>(v[IX(14)], -0.70710678f, -0.70710678f); // W^6
  v[IX(15)] = twc<DIR>(v[IX(15)], -0.92387953f,  0.38268343f); // W^9
  // Stage 2: DFT-4 over consecutive quads (k1 fixed); X[k1+4k2] -> logical 4k1+k2
  #pragma unroll
  for (int k1 = 0; k1 < 4; ++k1) {
    float2 a0 = v[IX(4*k1)], a1 = v[IX(4*k1+1)], a2 = v[IX(4*k1+2)], a3 = v[IX(4*k1+3)];
    float2 t0 = cadd(a0,a2), t1 = csub(a0,a2), t2 = cadd(a1,a3), d = csub(a1,a3);
    float2 t3 = (DIR < 0) ? make_float2(d.y,-d.x) : make_float2(-d.y,d.x);
    v[IX(4*k1)]   = cadd(t0,t2);
    v[IX(4*k1+1)] = cadd(t1,t3);
    v[IX(4*k1+2)] = csub(t0,t2);
    v[IX(4*k1+3)] = csub(t1,t3);
  }
  #undef IX
}

// Per-lane outer twiddles: twf[k] = exp(-2*pi*i*l*k/256) (forward).
__device__ __forceinline__ void make_twf(int l, float2* twf) {
  float s, c;
  sincospif((float)l * (-1.0f/128.0f), &s, &c);
  const float2 w = make_float2(c, s);
  twf[0] = make_float2(1.f, 0.f);
  #pragma unroll
  for (int k = 1; k < 16; ++k) twf[k] = cmul(twf[k-1], w);
}

// 256-pt FFT for one 16-lane group: v[j] holds x[l + 16*j] (REV1=false) or
// x at physical rho4(j) (REV1=true, for chaining). trbuf = group's 256 float2,
// XOR-swizzled (write (k1,n1) at [k1*16 + (n1^k1)]) -> conflict-free both sides.
// Output: X[l + 16*rho4(rr)] at physical reg rr. Intra-wave LDS, no barrier.
template<int DIR, bool REV1>
__device__ __forceinline__ void fft256g(float2* v, float2* trbuf, int l, const float2* twf) {
  fft16<DIR, REV1>(v);
  #pragma unroll
  for (int r = 0; r < 16; ++r) {
    const int k1 = REV1 ? r : rho4(r);
    float2 z = v[r];
    z = (DIR < 0) ? cmul(twf[k1], z) : cmulc(twf[k1], z);
    trbuf[(k1 << 4) | (l ^ k1)] = z;
  }
  SCHED_FENCE();
  #pragma unroll
  for (int j = 0; j < 16; ++j) v[j] = trbuf[(l << 4) | (j ^ l)];
  SCHED_FENCE();
  fft16<DIR, false>(v);
}

// ---------- Pass 1: row FFT (fp32 in) -> Bt[u][r] fp16 (transposed) ----------
__global__ __launch_bounds__(256) void k_pass1(const float* __restrict__ x,
    __half2* __restrict__ Bt, int img0, int istep) {
  __shared__ float2 trbuf[16 * 256];   // 32 KB
  __shared__ __half2 tile[256][17];    // 17 KB
  const int tid = threadIdx.x, g = tid >> 4, l = tid & 15;
  const int slot = blockIdx.y, img = img0 + slot * istep;
  float2 twf[16]; make_twf(l, twf);
  const float* xim = x + ((size_t)img << 16);
  __half2* bim = Bt + ((size_t)slot << 16);
  float2* tb = trbuf + (g << 8);
  #pragma unroll 1
  for (int it = 0; it < 4; ++it) {
    const int row = (blockIdx.x << 6) + (it << 4) + g;
    const float* xr = xim + (row << 8);
    float2 v[16];
    #pragma unroll
    for (int j = 0; j < 16; ++j) v[j] = make_float2(xr[l + (j << 4)], 0.f);
    fft256g<-1, false>(v, tb, l, twf);
    __syncthreads();   // previous tile flush complete
    #pragma unroll
    for (int rr = 0; rr < 16; ++rr)
      tile[l + (rho4(rr) << 4)][g] = f2h(v[rr]);
    __syncthreads();
    const int rbase = (blockIdx.x << 6) + (it << 4);
    const int rloc = tid & 15, ub = tid >> 4;
    #pragma unroll
    for (int jj = 0; jj < 16; ++jj) {
      const int u = (jj << 4) + ub;
      bim[(u << 8) + rbase + rloc] = tile[u][rloc];
    }
  }
}

// ------ Pass 2: col FFT + highpass mask + col IFFT; Bt[u][r] -> Ct[r][u] ------
__global__ __launch_bounds__(256) void k_pass2(const __half2* __restrict__ Bt,
    __half2* __restrict__ Ct, const int* __restrict__ cutoffs, int img0, int istep) {
  __shared__ float2 trbuf[16 * 256];
  __shared__ __half2 tile[256][17];
  const int tid = threadIdx.x, g = tid >> 4, l = tid & 15;
  const int slot = blockIdx.y, img = img0 + slot * istep;
  const int cut = cutoffs[img >> 6];   // 1..127
  float2 twf[16]; make_twf(l, twf);
  const __half2* bim = Bt + ((size_t)slot << 16);
  __half2* cim = Ct + ((size_t)slot << 16);
  float2* tb = trbuf + (g << 8);
  #pragma unroll 1
  for (int it = 0; it < 4; ++it) {
    const int u = (blockIdx.x << 6) + (it << 4) + g;
    const __half2* col = bim + (u << 8);
    float2 v[16];
    #pragma unroll
    for (int j = 0; j < 16; ++j) v[j] = h2f(col[l + (j << 4)]);
    fft256g<-1, false>(v, tb, l, twf);
    if ((u < cut) | (u >= 256 - cut)) {
      #pragma unroll
      for (int rr = 0; rr < 16; ++rr) {
        const int vi = l + (rho4(rr) << 4);
        if (vi < cut || vi >= 256 - cut) v[rr] = make_float2(0.f, 0.f);
      }
    }
    fft256g<1, true>(v, tb, l, twf);
    __syncthreads();
    #pragma unroll
    for (int rr = 0; rr < 16; ++rr)
      tile[l + (rho4(rr) << 4)][g] = f2h(v[rr]);
    __syncthreads();
    const int ubase = (blockIdx.x << 6) + (it << 4);
    const int cloc = tid & 15, rb = tid >> 4;
    #pragma unroll
    for (int jj = 0; jj < 16; ++jj) {
      const int r = (jj << 4) + rb;
      cim[(r << 8) + ubase + cloc] = tile[r][cloc];
    }
  }
}

// ---------- Pass 3: row IFFT + |.|/65536 -> out (direct stores) ----------
__global__ __launch_bounds__(256) void k_pass3(const __half2* __restrict__ Ct,
    float* __restrict__ out, int img0, int istep) {
  __shared__ float2 trbuf[16 * 256];
  const int tid = threadIdx.x, g = tid >> 4, l = tid & 15;
  const int slot = blockIdx.y, img = img0 + slot * istep;
  float2 twf[16]; make_twf(l, twf);
  const __half2* cim = Ct + ((size_t)slot << 16);
  float* oim = out + ((size_t)img << 16);
  float2* tb = trbuf + (g << 8);
  #pragma unroll 1
  for (int it = 0; it < 4; ++it) {
    const int row = (blockIdx.x << 6) + (it << 4) + g;
    const __half2* rp = cim + (row << 8);
    float2 v[16];
    #pragma unroll
    for (int j = 0; j < 16; ++j) v[j] = h2f(rp[l + (j << 4)]);
    fft256g<1, false>(v, tb, l, twf);
    float* orow = oim + (row << 8);
    #pragma unroll
    for (int rr = 0; rr < 16; ++rr) {
      const float2 z = v[rr];
      orow[l + (rho4(rr) << 4)] = sqrtf(z.x*z.x + z.y*z.y) * (1.f/65536.f);
    }
  }
}

// ------ Histogram: col FFT of Bt (fp16 row spectra), ring-energy bins ------
__global__ __launch_bounds__(256) void k_hist(const __half2* __restrict__ Bt,
    double* __restrict__ bins, int slot0, int sstep, int batch0) {
  __shared__ float2 trbuf[16 * 256];
  __shared__ float whist[4][132];
  const int tid = threadIdx.x, g = tid >> 4, l = tid & 15, wave = tid >> 6;
  const int lb = blockIdx.y;
  const int batch = batch0 + lb;
  const size_t slot = (size_t)(slot0 + lb * sstep);
  const int u = (blockIdx.x << 4) + g;
  float2 twf[16]; make_twf(l, twf);
  for (int i = tid & 63; i < 132; i += 64) whist[wave][i] = 0.f;
  __syncthreads();
  const __half2* col = Bt + (slot << 16) + (u << 8);
  float2 v[16];
  #pragma unroll
  for (int j = 0; j < 16; ++j) v[j] = h2f(col[l + (j << 4)]);
  float2* tb = trbuf + (g << 8);
  fft256g<-1, false>(v, tb, l, twf);
  const int fc = (u < 128) ? u + 1 : 256 - u;
  #pragma unroll
  for (int rr = 0; rr < 16; ++rr) {
    const int vi = l + (rho4(rr) << 4);
    const int fu = (vi < 128) ? vi + 1 : 256 - vi;
    const int seg = fu > fc ? fu : fc;
    const float2 z = v[rr];
    atomicAdd(&whist[wave][seg], z.x*z.x + z.y*z.y);
  }
  __syncthreads();
  for (int s = tid; s < 129; s += 256) {
    const float sum = whist[0][s] + whist[1][s] + whist[2][s] + whist[3][s];
    if (sum != 0.f) atomicAdd(&bins[batch * 129 + s], (double)sum);
  }
}

__global__ void k_cutoff(const double* __restrict__ bins, int* __restrict__ cutoffs) {
  const int b = threadIdx.x;
  if (b < 8) {
    const double* Bv = bins + b * 129;
    double total = 0.0;
    for (int s = 0; s < 129; ++s) total += Bv[s];
    const double target = 0.4 * total;
    double cum = Bv[0];
    int cut = 5;
    bool found = false;
    for (int s = 1; s <= 127; ++s) {
      cum += Bv[s];
      if (!found && cum >= target) { cut = s; found = true; }
    }
    cutoffs[b] = cut;
  }
}

extern "C" void kernel_launch(void* const* d_in, const int* in_sizes, int n_in,
                              void* d_out, int out_size, void* d_ws, size_t ws_size,
                              hipStream_t stream) {
  const float* x = (const float*)d_in[0];
  float* out = (float*)d_out;
  char* wsb = (char*)d_ws;
  double* bins    = (double*)wsb;          // 8*129 doubles
  int*    cutoffs = (int*)(wsb + 8448);
  char*   payload = wsb + RESERVE;

  size_t avail = (ws_size > RESERVE) ? ws_size - (size_t)RESERVE : 0;
  long long Gl = (long long)(avail / 524288);   // Bt + Ct, 256 KB each per image
  int G = (Gl > 512) ? 512 : (int)Gl;
  if (G < 1) G = 1;
  __half2* Bt = (__half2*)payload;
  __half2* Ct = (__half2*)(payload + (size_t)G * 262144);

  hipMemsetAsync(bins, 0, 8 * 129 * sizeof(double), stream);
  dim3 blk(256, 1, 1);

  if (G >= 512) {
    k_pass1<<<dim3(4, 512), blk, 0, stream>>>(x, Bt, 0, 1);
    k_hist <<<dim3(16, 8),  blk, 0, stream>>>(Bt, bins, 0, 64, 0);
    k_cutoff<<<dim3(1), dim3(64), 0, stream>>>(bins, cutoffs);
    k_pass2<<<dim3(4, 512), blk, 0, stream>>>(Bt, Ct, cutoffs, 0, 1);
    k_pass3<<<dim3(4, 512), blk, 0, stream>>>(Ct, out, 0, 1);
  } else {
    // Pre-pass on channel-0 images (slots 0..Gp-1), then grouped main pass.
    int Gp = G > 8 ? 8 : G;
    for (int b0 = 0; b0 < 8; b0 += Gp) {
      int n = (8 - b0 < Gp) ? (8 - b0) : Gp;
      k_pass1<<<dim3(4, n), blk, 0, stream>>>(x, Bt, b0 * 64, 64);
      k_hist <<<dim3(16, n), blk, 0, stream>>>(Bt, bins, 0, 1, b0);
    }
    k_cutoff<<<dim3(1), dim3(64), 0, stream>>>(bins, cutoffs);
    for (int g0 = 0; g0 < 512; g0 += G) {
      int n = (512 - g0 < G) ? (512 - g0) : G;
      k_pass1<<<dim3(4, n), blk, 0, stream>>>(x, Bt, g0, 1);
      k_pass2<<<dim3(4, n), blk, 0, stream>>>(Bt, Ct, cutoffs, g0, 1);
      k_pass3<<<dim3(4, n), blk, 0, stream>>>(Ct, out, g0, 1);
    }
  }
}